// Round 7
// baseline (516.382 us; speedup 1.0000x reference)
//
#include <hip/hip_runtime.h>
#include <hip/hip_cooperative_groups.h>

namespace cg = cooperative_groups;

#define TREES 32
#define PER   1023
#define NIPT  511
#define NINT  (TREES*NIPT)      // 16352
#define NLEAF (TREES*512)       // 16384
#define VLEAF 5000

typedef __bf16 bf16_t;
typedef bf16_t bf16x8 __attribute__((ext_vector_type(8)));
typedef float  f32x4  __attribute__((ext_vector_type(4)));

__device__ __forceinline__ float sigf(float x) { return 1.0f/(1.0f+__expf(-x)); }
__device__ __forceinline__ float tanh_fast(float x) { return 2.0f/(1.0f+__expf(-2.0f*x)) - 1.0f; }

__device__ __forceinline__ bf16x8 to_bf16x8(const float* p) {
  float4 a = *(const float4*)p;
  float4 b = *(const float4*)(p+4);
  bf16x8 r;
  r[0]=(bf16_t)a.x; r[1]=(bf16_t)a.y; r[2]=(bf16_t)a.z; r[3]=(bf16_t)a.w;
  r[4]=(bf16_t)b.x; r[5]=(bf16_t)b.y; r[6]=(bf16_t)b.z; r[7]=(bf16_t)b.w;
  return r;
}
__device__ __forceinline__ bf16x8 zero_bf16x8() {
  bf16x8 r;
  #pragma unroll
  for (int i=0;i<8;++i) r[i]=(bf16_t)0.0f;
  return r;
}

// ---- LDS B-staging: N-major [NCOLS][KB bytes] at ROWB stride ----
template<int NCOLS, int KB, int ROWB>
__device__ __forceinline__ void stage_B(const bf16_t* __restrict__ src, char* lds, int tid) {
  const char* s = (const char*)src;
  for (int off = tid*16; off < NCOLS*KB; off += 512*16) {
    int col = off / KB;
    int ko  = off - col*KB;
    *(float4*)(lds + col*ROWB + ko) = *(const float4*)(s + off);
  }
}
__device__ __forceinline__ bf16x8 ldsB(const char* lds, int col, int kb, int rowb) {
  return *(const bf16x8*)(lds + col*rowb + kb);
}

// =================== device bodies (shared by fused + fallback) ===============

__device__ __forceinline__ void dev_convert(
    const float* __restrict__ W_iou, const float* __restrict__ W_f,
    const float* __restrict__ U_iou, const float* __restrict__ U_f,
    const float* __restrict__ W_leaf,
    bf16_t* __restrict__ Wpt, bf16_t* __restrict__ Upt, bf16_t* __restrict__ WLt,
    int start, int stride)
{
  const int n1 = 512*128;
  const int total = 2*n1 + 384*192;
  for (int idx = start; idx < total; idx += stride) {
    if (idx < n1) {
      int cc = idx >> 7, k = idx & 127;
      Wpt[idx] = (bf16_t)(cc < 384 ? W_iou[k*384+cc] : W_f[k*128+cc-384]);
    } else if (idx < 2*n1) {
      int q = idx - n1;
      int cc = q >> 7, k = q & 127;
      Upt[q] = (bf16_t)(cc < 384 ? U_iou[k*384+cc] : U_f[k*128+cc-384]);
    } else {
      int q = idx - 2*n1;
      int cc = q / 192, k = q - cc*192;
      int cm = cc < 128 ? cc : cc + 128;
      WLt[q] = (bf16_t)W_leaf[(k>>6)*32768 + (k&63)*512 + cm];
    }
  }
}

// one 16-row prep tile: wxb[row] = bf16([emb@W_iou+b_iou | emb@W_f+b_f])
__device__ __forceinline__ void dev_prep_tile(const char* Blds,
    const int* __restrict__ features, const float* __restrict__ emb_res,
    const float* __restrict__ b_iou, const float* __restrict__ b_f,
    bf16_t* __restrict__ wxb, int row0, int lane, int lg, int col0, int cs)
{
  int rowA = row0 + (lane&15);
  if (rowA >= NINT) rowA = NINT-1;
  unsigned tree = (unsigned)rowA / 511u;
  int local = rowA - tree*511u;
  int feat = features[tree*1023 + local];
  const float* ep = emb_res + (size_t)feat*128 + lg*8;

  bf16x8 a[4];
  #pragma unroll
  for (int ks=0; ks<4; ++ks) a[ks] = to_bf16x8(ep + ks*32);

  f32x4 acc[8];
  #pragma unroll
  for (int j=0;j<8;++j) acc[j] = (f32x4){0.f,0.f,0.f,0.f};
  #pragma unroll
  for (int ks=0; ks<4; ++ks) {
    #pragma unroll
    for (int j=0; j<8; ++j) {
      bf16x8 b = ldsB(Blds, cs*128 + j*16 + col0, ks*64 + lg*16, 264);
      acc[j] = __builtin_amdgcn_mfma_f32_16x16x32_bf16(a[ks], b, acc[j], 0,0,0);
    }
  }
  #pragma unroll
  for (int j=0; j<8; ++j) {
    int c = cs*128 + j*16 + col0;
    float bias = (c < 384) ? b_iou[c] : b_f[c-384];
    #pragma unroll
    for (int r=0; r<4; ++r) {
      int ci = row0 + lg*4 + r;
      if (ci >= NINT) ci = NINT-1;
      wxb[(size_t)ci*512 + c] = (bf16_t)(acc[j][r] + bias);
    }
  }
}

// one 16-leaf tile: block-diag K=192 GEMM, N=384 [gi|gg|go]
__device__ __forceinline__ void dev_leaf_tile(const char* Blds,
    const int* __restrict__ features, const int* __restrict__ vocabs,
    const float* __restrict__ emb_leaf, const float* __restrict__ b_leaf,
    bf16_t* __restrict__ h, float* __restrict__ cst,
    int base, int lane, int lg, int col0, int cs)
{
  int rA = base + (lane&15);
  int treeA = rA>>9, loA = rA&511;
  int nodeA = treeA*1023 + 511 + loA;
  int kkA = vocabs[nodeA]-1;
  int featA = features[nodeA];
  const float* xp = emb_leaf + ((size_t)kkA*VLEAF + featA)*64;

  f32x4 acc[6];
  #pragma unroll
  for (int j=0;j<6;++j) acc[j] = (f32x4){0.f,0.f,0.f,0.f};
  #pragma unroll
  for (int ks=0; ks<6; ++ks) {
    int k0 = ks*32 + lg*8;
    bf16x8 a = ((k0>>6) == kkA) ? to_bf16x8(xp + (k0&63)) : zero_bf16x8();
    #pragma unroll
    for (int g=0; g<3; ++g) {
      #pragma unroll
      for (int s=0; s<2; ++s) {
        bf16x8 b = ldsB(Blds, g*128 + cs*32 + s*16 + col0, ks*64 + lg*16, 392);
        acc[g*2+s] = __builtin_amdgcn_mfma_f32_16x16x32_bf16(a, b, acc[g*2+s], 0,0,0);
      }
    }
  }
  #pragma unroll
  for (int r=0; r<4; ++r) {
    int L = base + lg*4 + r;
    int tree = L>>9, lo = L&511;
    int node = tree*1023 + 511 + lo;
    int kk = vocabs[node]-1;
    const float* bl = b_leaf + kk*512;
    #pragma unroll
    for (int s=0; s<2; ++s) {
      int cc = cs*32 + s*16 + col0;
      float gi = acc[s][r]   + bl[cc];
      float gg = acc[2+s][r] + bl[256+cc];
      float go = acc[4+s][r] + bl[384+cc];
      float ck = sigf(gi)*tanh_fast(gg);
      float hk = sigf(go)*tanh_fast(ck);
      cst[(size_t)node*128+cc] = ck;
      h[(size_t)node*128+cc] = (bf16_t)hk;
    }
  }
}

// one 8-parent level tile (16 child rows), U staged in LDS at stride 264
__device__ __forceinline__ void dev_level_tile(const char* Blds,
    const bf16_t* __restrict__ wxb, bf16_t* __restrict__ h, float* __restrict__ cst,
    int shift, int ptile0, int lane, int lg, int col0, int cs)
{
  const int cnt = 1<<shift;
  int rr = lane&15;
  int fpA = ptile0 + (rr>>1);
  int treeA = fpA>>shift, loA = fpA&(cnt-1);
  int chA = treeA*1023 + 2*(cnt-1+loA) + 1 + (rr&1);
  const bf16_t* hp = h + (size_t)chA*128 + lg*8;
  bf16x8 a[4];
  #pragma unroll
  for (int ks=0; ks<4; ++ks) a[ks] = *(const bf16x8*)(hp + ks*32);

  float wxv[2][2][4], cch[2][2][2];
  int pnode[2];
  #pragma unroll
  for (int pp=0; pp<2; ++pp) {
    int fp = ptile0 + lg*2 + pp;
    int tree = fp>>shift, lo = fp&(cnt-1);
    int plocal = cnt-1+lo;
    pnode[pp] = tree*1023 + plocal;
    size_t chl = ((size_t)tree*1023 + 2*plocal + 1)*128;
    size_t wb = ((size_t)tree*511 + plocal)*512;
    #pragma unroll
    for (int s2=0; s2<2; ++s2) {
      int hcol = cs*32 + s2*16 + col0;
      #pragma unroll
      for (int g=0; g<4; ++g) wxv[pp][s2][g] = (float)wxb[wb + g*128 + hcol];
      cch[pp][s2][0] = cst[chl + hcol];
      cch[pp][s2][1] = cst[chl + 128 + hcol];
    }
  }

  f32x4 acc[8];
  #pragma unroll
  for (int gs=0; gs<8; ++gs) acc[gs] = (f32x4){0.f,0.f,0.f,0.f};
  #pragma unroll
  for (int ks=0; ks<4; ++ks) {
    #pragma unroll
    for (int gs=0; gs<8; ++gs) {
      bf16x8 b = ldsB(Blds, (gs>>1)*128 + cs*32 + (gs&1)*16 + col0, ks*64 + lg*16, 264);
      acc[gs] = __builtin_amdgcn_mfma_f32_16x16x32_bf16(a[ks], b, acc[gs], 0,0,0);
    }
  }

  #pragma unroll
  for (int pp=0; pp<2; ++pp) {
    #pragma unroll
    for (int s2=0; s2<2; ++s2) {
      int hcol = cs*32 + s2*16 + col0;
      float iv = acc[s2][2*pp]   + acc[s2][2*pp+1]   + wxv[pp][s2][0];
      float ov = acc[2+s2][2*pp] + acc[2+s2][2*pp+1] + wxv[pp][s2][1];
      float uv = acc[4+s2][2*pp] + acc[4+s2][2*pp+1] + wxv[pp][s2][2];
      float wf = wxv[pp][s2][3];
      float fl = sigf(acc[6+s2][2*pp]   + wf);
      float fr = sigf(acc[6+s2][2*pp+1] + wf);
      float cf = fl*cch[pp][s2][0] + fr*cch[pp][s2][1];
      float cn = sigf(iv)*tanh_fast(uv) + cf;
      float hn = sigf(ov)*tanh_fast(cn);
      cst[(size_t)pnode[pp]*128 + hcol] = cn;
      h[(size_t)pnode[pp]*128 + hcol] = (bf16_t)hn;
    }
  }
}

// tail levels n=4..9 for one tree + fused root head (block-local)
__device__ __forceinline__ void dev_tail(const char* Blds,
    const bf16_t* __restrict__ wxb, bf16_t* __restrict__ h, float* __restrict__ cst,
    const float* __restrict__ Wm, const float* __restrict__ bm,
    const float* __restrict__ Wv, const float* __restrict__ bv,
    const float* __restrict__ eps, float* __restrict__ out, float* hs,
    int tree, int tid, int lane, int rg, int cs, int lg, int col0)
{
  const size_t hb = (size_t)tree*1023*128;
  for (int n = 4; n <= 9; ++n) {
    const int P = 1 << (9-n);
    const int rows2 = 2*P;
    const int mtiles = (rows2 >= 16) ? (rows2 >> 4) : 1;
    const int cbase = 2*P - 1;

    for (int mt = rg; mt < mtiles; mt += 2) {
      const int rb = mt*16;
      int cr = rb + (lane&15);
      if (cr >= rows2) cr = 0;
      const bf16_t* hp = h + hb + (size_t)(cbase + cr)*128 + lg*8;
      bf16x8 a[4];
      #pragma unroll
      for (int ks=0; ks<4; ++ks) a[ks] = *(const bf16x8*)(hp + ks*32);

      float wxv[2][2][4], cch[2][2][2];
      int pj[2], plocal[2];
      #pragma unroll
      for (int pp=0; pp<2; ++pp) {
        pj[pp] = (rb>>1) + lg*2 + pp;
        plocal[pp] = P - 1 + pj[pp];
        if (pj[pp] < P) {
          size_t wb = ((size_t)tree*511 + plocal[pp])*512;
          size_t chl = hb + (size_t)(cbase + 2*pj[pp])*128;
          #pragma unroll
          for (int s2=0; s2<2; ++s2) {
            int hcol = cs*32 + s2*16 + col0;
            #pragma unroll
            for (int g=0; g<4; ++g) wxv[pp][s2][g] = (float)wxb[wb + g*128 + hcol];
            cch[pp][s2][0] = cst[chl + hcol];
            cch[pp][s2][1] = cst[chl + 128 + hcol];
          }
        }
      }

      f32x4 acc[8];
      #pragma unroll
      for (int gs=0; gs<8; ++gs) acc[gs] = (f32x4){0.f,0.f,0.f,0.f};
      #pragma unroll
      for (int ks=0; ks<4; ++ks) {
        #pragma unroll
        for (int gs=0; gs<8; ++gs) {
          bf16x8 b = ldsB(Blds, (gs>>1)*128 + cs*32 + (gs&1)*16 + col0, ks*64 + lg*16, 264);
          acc[gs] = __builtin_amdgcn_mfma_f32_16x16x32_bf16(a[ks], b, acc[gs], 0,0,0);
        }
      }

      #pragma unroll
      for (int pp=0; pp<2; ++pp) {
        if (pj[pp] < P) {
          size_t pno = hb + (size_t)plocal[pp]*128;
          #pragma unroll
          for (int s2=0; s2<2; ++s2) {
            int hcol = cs*32 + s2*16 + col0;
            float iv = acc[s2][2*pp]   + acc[s2][2*pp+1]   + wxv[pp][s2][0];
            float ov = acc[2+s2][2*pp] + acc[2+s2][2*pp+1] + wxv[pp][s2][1];
            float uv = acc[4+s2][2*pp] + acc[4+s2][2*pp+1] + wxv[pp][s2][2];
            float wf = wxv[pp][s2][3];
            float fl = sigf(acc[6+s2][2*pp]   + wf);
            float fr = sigf(acc[6+s2][2*pp+1] + wf);
            float cf = fl*cch[pp][s2][0] + fr*cch[pp][s2][1];
            float cn = sigf(iv)*tanh_fast(uv) + cf;
            float hn = sigf(ov)*tanh_fast(cn);
            cst[pno + hcol] = cn;
            h[pno + hcol] = (bf16_t)hn;
            if (n == 9) hs[hcol] = hn;
          }
        }
      }
    }
    __threadfence_block();
    __syncthreads();
  }

  if (tid < 64) {
    const int j = tid;
    float am = 0.f, av = 0.f;
    #pragma unroll 4
    for (int i=0;i<128;++i) {
      float hv = hs[i];
      am += hv*Wm[i*64+j];
      av += hv*Wv[i*64+j];
    }
    float zm = am + bm[j];
    float zv = av + bv[j];
    int idx = tree*64 + j;
    out[idx]        = zm + eps[idx]*__expf(0.5f*zv);
    out[2048 + idx] = zm;
    out[4096 + idx] = zv;
  }
}

// =================== single cooperative kernel ===============================
__global__ __launch_bounds__(512) void fused_all(
    const int* __restrict__ features, const int* __restrict__ vocabs,
    const float* __restrict__ eps,
    const float* __restrict__ emb_res, const float* __restrict__ emb_leaf,
    const float* __restrict__ W_leaf, const float* __restrict__ b_leaf,
    const float* __restrict__ W_iou, const float* __restrict__ b_iou,
    const float* __restrict__ U_iou,
    const float* __restrict__ W_f, const float* __restrict__ b_f,
    const float* __restrict__ U_f,
    const float* __restrict__ Wm, const float* __restrict__ bm,
    const float* __restrict__ Wv, const float* __restrict__ bv,
    bf16_t* __restrict__ Wpt, bf16_t* __restrict__ Upt, bf16_t* __restrict__ WLt,
    bf16_t* __restrict__ wxb, bf16_t* __restrict__ h, float* __restrict__ cst,
    float* __restrict__ out)
{
  __shared__ __align__(16) char Blds[150528];
  __shared__ float hs[128];
  const int tid = threadIdx.x, wave = tid>>6, lane = tid&63;
  const int rg = wave>>2, cs = wave&3;
  const int lg = lane>>4, col0 = lane&15;
  const int blk = blockIdx.x;
  cg::grid_group grid = cg::this_grid();

  // phase 0: weight conversion
  dev_convert(W_iou, W_f, U_iou, U_f, W_leaf, Wpt, Upt, WLt, blk*512 + tid, 256*512);
  __threadfence();
  grid.sync();

  // phase A: prep (blocks 0-127) | leaf (blocks 128-255)
  if (blk < 128) {
    stage_B<512,256,264>(Wpt, Blds, tid);
    __syncthreads();
    #pragma unroll
    for (int mi=0; mi<4; ++mi) {
      int mt = rg + mi*2;
      dev_prep_tile(Blds, features, emb_res, b_iou, b_f, wxb,
                    blk*128 + mt*16, lane, lg, col0, cs);
    }
  } else {
    stage_B<384,384,392>(WLt, Blds, tid);
    __syncthreads();
    #pragma unroll
    for (int mi=0; mi<4; ++mi) {
      int mt = rg + mi*2;
      dev_leaf_tile(Blds, features, vocabs, emb_leaf, b_leaf, h, cst,
                    (blk-128)*128 + mt*16, lane, lg, col0, cs);
    }
  }
  __threadfence();
  grid.sync();

  // stage U once; reused for all levels
  stage_B<512,256,264>(Upt, Blds, tid);
  __syncthreads();

  // n=1: 8192 parents, 32/block
  #pragma unroll
  for (int mi=0; mi<2; ++mi) {
    int mt = rg + mi*2;
    dev_level_tile(Blds, wxb, h, cst, 8, blk*32 + mt*8, lane, lg, col0, cs);
  }
  __threadfence();
  grid.sync();

  // n=2: 4096 parents, 16/block
  dev_level_tile(Blds, wxb, h, cst, 7, blk*16 + rg*8, lane, lg, col0, cs);
  __threadfence();
  grid.sync();

  // n=3: 2048 parents, 8/block (rowgroup 0 only)
  if (rg == 0)
    dev_level_tile(Blds, wxb, h, cst, 6, blk*8, lane, lg, col0, cs);
  __threadfence();
  grid.sync();

  // tail n=4..9 + root head: one block per tree
  if (blk >= 32) return;
  dev_tail(Blds, wxb, h, cst, Wm, bm, Wv, bv, eps, out, hs,
           blk, tid, lane, rg, cs, lg, col0);
}

// =================== fallback kernels (round-5 pipeline) ======================
__global__ __launch_bounds__(256) void k_convert(
    const float* W_iou, const float* W_f, const float* U_iou, const float* U_f,
    const float* W_leaf, bf16_t* Wpt, bf16_t* Upt, bf16_t* WLt)
{
  dev_convert(W_iou, W_f, U_iou, U_f, W_leaf, Wpt, Upt, WLt,
              blockIdx.x*256 + threadIdx.x, gridDim.x*256);
}

__global__ __launch_bounds__(512) void k_prep(
    const int* features, const float* emb_res,
    const float* b_iou, const float* b_f, const bf16_t* Wpt, bf16_t* wxb)
{
  __shared__ __align__(16) char Blds[150528];
  const int tid = threadIdx.x, wave = tid>>6, lane = tid&63;
  const int rg = wave>>2, cs = wave&3, lg = lane>>4, col0 = lane&15;
  stage_B<512,256,264>(Wpt, Blds, tid);
  __syncthreads();
  #pragma unroll
  for (int mi=0; mi<2; ++mi) {
    int mt = rg + mi*2;
    dev_prep_tile(Blds, features, emb_res, b_iou, b_f, wxb,
                  blockIdx.x*64 + mt*16, lane, lg, col0, cs);
  }
}

__global__ __launch_bounds__(512) void k_leaf(
    const int* features, const int* vocabs, const float* emb_leaf,
    const float* b_leaf, const bf16_t* WLt, bf16_t* h, float* cst)
{
  __shared__ __align__(16) char Blds[150528];
  const int tid = threadIdx.x, wave = tid>>6, lane = tid&63;
  const int rg = wave>>2, cs = wave&3, lg = lane>>4, col0 = lane&15;
  stage_B<384,384,392>(WLt, Blds, tid);
  __syncthreads();
  #pragma unroll
  for (int mi=0; mi<2; ++mi) {
    int mt = rg + mi*2;
    dev_leaf_tile(Blds, features, vocabs, emb_leaf, b_leaf, h, cst,
                  blockIdx.x*64 + mt*16, lane, lg, col0, cs);
  }
}

__global__ __launch_bounds__(512) void k_level(
    const bf16_t* Upt, const bf16_t* wxb, bf16_t* h, float* cst, int shift)
{
  __shared__ __align__(16) char Blds[150528];
  const int tid = threadIdx.x, wave = tid>>6, lane = tid&63;
  const int rg = wave>>2, cs = wave&3, lg = lane>>4, col0 = lane&15;
  stage_B<512,256,264>(Upt, Blds, tid);
  __syncthreads();
  #pragma unroll
  for (int mi=0; mi<2; ++mi) {
    int mt = rg + mi*2;
    dev_level_tile(Blds, wxb, h, cst, shift, blockIdx.x*32 + mt*8, lane, lg, col0, cs);
  }
}

__global__ __launch_bounds__(512) void k_tail(
    const bf16_t* Upt, const bf16_t* wxb, bf16_t* h, float* cst,
    const float* Wm, const float* bm, const float* Wv, const float* bv,
    const float* eps, float* out)
{
  __shared__ __align__(16) char Blds[150528];
  __shared__ float hs[128];
  const int tid = threadIdx.x, wave = tid>>6, lane = tid&63;
  const int rg = wave>>2, cs = wave&3, lg = lane>>4, col0 = lane&15;
  stage_B<512,256,264>(Upt, Blds, tid);
  __syncthreads();
  dev_tail(Blds, wxb, h, cst, Wm, bm, Wv, bv, eps, out, hs,
           blockIdx.x, tid, lane, rg, cs, lg, col0);
}

// =================== host launcher ============================================
extern "C" void kernel_launch(void* const* d_in, const int* in_sizes, int n_in,
                              void* d_out, int out_size, void* d_ws, size_t ws_size,
                              hipStream_t stream) {
  const int*   features = (const int*)  d_in[0];
  const int*   vocabs   = (const int*)  d_in[1];
  // d_in[2..5]: static topology (derived in-kernel)
  const float* eps      = (const float*)d_in[6];
  const float* emb_res  = (const float*)d_in[7];
  const float* emb_leaf = (const float*)d_in[8];
  const float* W_leaf   = (const float*)d_in[9];
  const float* b_leaf   = (const float*)d_in[10];
  const float* W_iou    = (const float*)d_in[11];
  const float* b_iou    = (const float*)d_in[12];
  const float* U_iou    = (const float*)d_in[13];
  const float* W_f      = (const float*)d_in[14];
  const float* b_f      = (const float*)d_in[15];
  const float* U_f      = (const float*)d_in[16];
  const float* Wm       = (const float*)d_in[17];
  const float* bm       = (const float*)d_in[18];
  const float* Wv       = (const float*)d_in[19];
  const float* bv       = (const float*)d_in[20];

  char* wsb = (char*)d_ws;
  bf16_t* h   = (bf16_t*)wsb;                                   // NNODES*128 bf16
  float*  cst = (float*)(wsb + 8388608);                        // NNODES*128 f32
  bf16_t* wxb = (bf16_t*)(wsb + 8388608 + 16777216);            // NINT*512 bf16
  bf16_t* Wpt = (bf16_t*)(wsb + 8388608 + 16777216 + 33554432);
  bf16_t* Upt = Wpt + 512*128;
  bf16_t* WLt = Upt + 512*128;
  float* out = (float*)d_out;

  void* args[] = {
    (void*)&features, (void*)&vocabs, (void*)&eps,
    (void*)&emb_res, (void*)&emb_leaf,
    (void*)&W_leaf, (void*)&b_leaf,
    (void*)&W_iou, (void*)&b_iou, (void*)&U_iou,
    (void*)&W_f, (void*)&b_f, (void*)&U_f,
    (void*)&Wm, (void*)&bm, (void*)&Wv, (void*)&bv,
    (void*)&Wpt, (void*)&Upt, (void*)&WLt,
    (void*)&wxb, (void*)&h, (void*)&cst, (void*)&out
  };
  hipError_t err = hipLaunchCooperativeKernel((const void*)fused_all,
                                              dim3(256), dim3(512),
                                              args, 0, stream);
  if (err != hipSuccess) {
    (void)hipGetLastError();   // clear, then fall back to multi-launch pipeline
    k_convert<<<200, 256, 0, stream>>>(W_iou, W_f, U_iou, U_f, W_leaf, Wpt, Upt, WLt);
    k_prep<<<256, 512, 0, stream>>>(features, emb_res, b_iou, b_f, Wpt, wxb);
    k_leaf<<<256, 512, 0, stream>>>(features, vocabs, emb_leaf, b_leaf, WLt, h, cst);
    k_level<<<256, 512, 0, stream>>>(Upt, wxb, h, cst, 8);  // n=1
    k_level<<<128, 512, 0, stream>>>(Upt, wxb, h, cst, 7);  // n=2
    k_level<<< 64, 512, 0, stream>>>(Upt, wxb, h, cst, 6);  // n=3
    k_tail<<<TREES, 512, 0, stream>>>(Upt, wxb, h, cst, Wm, bm, Wv, bv, eps, out);
  }
}

// Round 8
// 146.118 us; speedup vs baseline: 3.5340x; 3.5340x over previous
//
#include <hip/hip_runtime.h>

#define TREES 32
#define PER   1023
#define NIPT  511
#define NINT  (TREES*NIPT)      // 16352
#define NLEAF (TREES*512)       // 16384
#define VLEAF 5000

typedef __bf16 bf16_t;
typedef bf16_t bf16x8 __attribute__((ext_vector_type(8)));
typedef float  f32x4  __attribute__((ext_vector_type(4)));

__device__ __forceinline__ float sigf(float x) { return 1.0f/(1.0f+__expf(-x)); }
__device__ __forceinline__ float tanh_fast(float x) { return 2.0f/(1.0f+__expf(-2.0f*x)) - 1.0f; }

__device__ __forceinline__ bf16x8 to_bf16x8(const float* p) {
  float4 a = *(const float4*)p;
  float4 b = *(const float4*)(p+4);
  bf16x8 r;
  r[0]=(bf16_t)a.x; r[1]=(bf16_t)a.y; r[2]=(bf16_t)a.z; r[3]=(bf16_t)a.w;
  r[4]=(bf16_t)b.x; r[5]=(bf16_t)b.y; r[6]=(bf16_t)b.z; r[7]=(bf16_t)b.w;
  return r;
}
__device__ __forceinline__ bf16x8 zero_bf16x8() {
  bf16x8 r;
  #pragma unroll
  for (int i=0;i<8;++i) r[i]=(bf16_t)0.0f;
  return r;
}
__device__ __forceinline__ bf16x8 ldsB(const char* lds, int col, int kb, int rowb) {
  return *(const bf16x8*)(lds + col*rowb + kb);
}

// ---- stage [Wa|Wb] (fp32, row-major KxN) -> LDS N-major [512 cols][128 k] bf16, stride 264B
// thread t = column; loads are lane-consecutive (coalesced); 16 ds_write_b128 per thread
__device__ __forceinline__ void stage_WU(const float* __restrict__ Wa, int lda,
                                         const float* __restrict__ Wb, int ldb,
                                         char* lds, int tid) {
  const float* src; int ld;
  if (tid < 384) { src = Wa + tid; ld = lda; }
  else           { src = Wb + (tid-384); ld = ldb; }
  #pragma unroll
  for (int k0 = 0; k0 < 128; k0 += 8) {
    bf16x8 r;
    #pragma unroll
    for (int i=0;i<8;++i) r[i] = (bf16_t)src[(k0+i)*ld];
    *(bf16x8*)(lds + tid*264 + k0*2) = r;
  }
}

// ---- stage W_leaf (3 vocabs, 64x512 each) -> LDS [384 cols=[gi|gg|go]][192 k block-diag], stride 392B
__device__ __forceinline__ void stage_WL(const float* __restrict__ W_leaf, char* lds, int tid) {
  if (tid < 384) {
    int cm = tid < 128 ? tid : tid + 128;      // [gi,gg,go] from [gi,gf,gg,go]
    #pragma unroll
    for (int k0 = 0; k0 < 192; k0 += 8) {
      bf16x8 r;
      #pragma unroll
      for (int i=0;i<8;++i) {
        int k = k0+i;
        r[i] = (bf16_t)W_leaf[(k>>6)*32768 + (k&63)*512 + cm];
      }
      *(bf16x8*)(lds + tid*392 + k0*2) = r;
    }
  }
}

// =================== tile bodies ===============

__device__ __forceinline__ void dev_prep_tile(const char* Blds,
    const int* __restrict__ features, const float* __restrict__ emb_res,
    const float* __restrict__ b_iou, const float* __restrict__ b_f,
    bf16_t* __restrict__ wxb, int row0, int lane, int lg, int col0, int cs)
{
  int rowA = row0 + (lane&15);
  if (rowA >= NINT) rowA = NINT-1;
  unsigned tree = (unsigned)rowA / 511u;
  int local = rowA - tree*511u;
  int feat = features[tree*1023 + local];
  const float* ep = emb_res + (size_t)feat*128 + lg*8;

  bf16x8 a[4];
  #pragma unroll
  for (int ks=0; ks<4; ++ks) a[ks] = to_bf16x8(ep + ks*32);

  f32x4 acc[8];
  #pragma unroll
  for (int j=0;j<8;++j) acc[j] = (f32x4){0.f,0.f,0.f,0.f};
  #pragma unroll
  for (int ks=0; ks<4; ++ks) {
    #pragma unroll
    for (int j=0; j<8; ++j) {
      bf16x8 b = ldsB(Blds, cs*128 + j*16 + col0, ks*64 + lg*16, 264);
      acc[j] = __builtin_amdgcn_mfma_f32_16x16x32_bf16(a[ks], b, acc[j], 0,0,0);
    }
  }
  #pragma unroll
  for (int j=0; j<8; ++j) {
    int c = cs*128 + j*16 + col0;
    float bias = (c < 384) ? b_iou[c] : b_f[c-384];
    #pragma unroll
    for (int r=0; r<4; ++r) {
      int ci = row0 + lg*4 + r;
      if (ci >= NINT) ci = NINT-1;
      wxb[(size_t)ci*512 + c] = (bf16_t)(acc[j][r] + bias);
    }
  }
}

__device__ __forceinline__ void dev_leaf_tile(const char* Blds,
    const int* __restrict__ features, const int* __restrict__ vocabs,
    const float* __restrict__ emb_leaf, const float* __restrict__ b_leaf,
    bf16_t* __restrict__ h, float* __restrict__ cst,
    int base, int lane, int lg, int col0, int cs)
{
  int rA = base + (lane&15);
  int treeA = rA>>9, loA = rA&511;
  int nodeA = treeA*1023 + 511 + loA;
  int kkA = vocabs[nodeA]-1;
  int featA = features[nodeA];
  const float* xp = emb_leaf + ((size_t)kkA*VLEAF + featA)*64;

  f32x4 acc[6];
  #pragma unroll
  for (int j=0;j<6;++j) acc[j] = (f32x4){0.f,0.f,0.f,0.f};
  #pragma unroll
  for (int ks=0; ks<6; ++ks) {
    int k0 = ks*32 + lg*8;
    bf16x8 a = ((k0>>6) == kkA) ? to_bf16x8(xp + (k0&63)) : zero_bf16x8();
    #pragma unroll
    for (int g=0; g<3; ++g) {
      #pragma unroll
      for (int s=0; s<2; ++s) {
        bf16x8 b = ldsB(Blds, g*128 + cs*32 + s*16 + col0, ks*64 + lg*16, 392);
        acc[g*2+s] = __builtin_amdgcn_mfma_f32_16x16x32_bf16(a, b, acc[g*2+s], 0,0,0);
      }
    }
  }
  #pragma unroll
  for (int r=0; r<4; ++r) {
    int L = base + lg*4 + r;
    int tree = L>>9, lo = L&511;
    int node = tree*1023 + 511 + lo;
    int kk = vocabs[node]-1;
    const float* bl = b_leaf + kk*512;
    #pragma unroll
    for (int s=0; s<2; ++s) {
      int cc = cs*32 + s*16 + col0;
      float gi = acc[s][r]   + bl[cc];
      float gg = acc[2+s][r] + bl[256+cc];
      float go = acc[4+s][r] + bl[384+cc];
      float ck = sigf(gi)*tanh_fast(gg);
      float hk = sigf(go)*tanh_fast(ck);
      cst[(size_t)node*128+cc] = ck;
      h[(size_t)node*128+cc] = (bf16_t)hk;
    }
  }
}

// =================== kernel 1: prep (blocks 0-255) | leaf (blocks 256-511) ====
__global__ __launch_bounds__(512) void k_prep_leaf(
    const int* __restrict__ features, const int* __restrict__ vocabs,
    const float* __restrict__ emb_res, const float* __restrict__ emb_leaf,
    const float* __restrict__ W_iou, const float* __restrict__ b_iou,
    const float* __restrict__ W_f, const float* __restrict__ b_f,
    const float* __restrict__ W_leaf, const float* __restrict__ b_leaf,
    bf16_t* __restrict__ wxb, bf16_t* __restrict__ h, float* __restrict__ cst)
{
  __shared__ __align__(16) char Blds[150528];
  const int tid = threadIdx.x, wave = tid>>6, lane = tid&63;
  const int rg = wave>>2, cs = wave&3, lg = lane>>4, col0 = lane&15;

  if (blockIdx.x < 256) {
    stage_WU(W_iou, 384, W_f, 128, Blds, tid);
    __syncthreads();
    #pragma unroll
    for (int mi=0; mi<2; ++mi) {
      int mt = rg + mi*2;
      dev_prep_tile(Blds, features, emb_res, b_iou, b_f, wxb,
                    blockIdx.x*64 + mt*16, lane, lg, col0, cs);
    }
  } else {
    stage_WL(W_leaf, Blds, tid);
    __syncthreads();
    #pragma unroll
    for (int mi=0; mi<2; ++mi) {
      int mt = rg + mi*2;
      dev_leaf_tile(Blds, features, vocabs, emb_leaf, b_leaf, h, cst,
                    (int)(blockIdx.x-256)*64 + mt*16, lane, lg, col0, cs);
    }
  }
}

// =================== kernel 2: levels 1+2 fused; order-1 state in LDS =========
// 256 blocks; block owns 16 order-2 subtrees (one tree each: 8 blocks/tree)
__global__ __launch_bounds__(512) void k_lvl12(
    const float* __restrict__ U_iou, const float* __restrict__ U_f,
    const bf16_t* __restrict__ wxb, bf16_t* __restrict__ h, float* __restrict__ cst)
{
  __shared__ __align__(16) char Blds[135168];          // 512 x 264
  __shared__ __align__(16) bf16_t st_h[32][136];
  __shared__ float st_c[32][132];
  const int tid = threadIdx.x, wave = tid>>6, lane = tid&63;
  const int rg = wave>>2, cs = wave&3, lg = lane>>4, col0 = lane&15;
  const int blk = blockIdx.x;

  stage_WU(U_iou, 384, U_f, 128, Blds, tid);
  __syncthreads();

  // ---- n=1 (shift=8): 32 order-1 parents, flat [32*blk, 32*blk+32)
  #pragma unroll
  for (int mi=0; mi<2; ++mi) {
    const int mt = rg + mi*2;
    const int ptile0 = blk*32 + mt*8;
    int rr = lane&15;
    int fpA = ptile0 + (rr>>1);
    int treeA = fpA>>8, loA = fpA&255;
    int chA = treeA*1023 + 2*(255+loA) + 1 + (rr&1);
    const bf16_t* hp = h + (size_t)chA*128 + lg*8;
    bf16x8 a[4];
    #pragma unroll
    for (int ks=0; ks<4; ++ks) a[ks] = *(const bf16x8*)(hp + ks*32);

    float wxv[2][2][4], cch[2][2][2];
    #pragma unroll
    for (int pp=0; pp<2; ++pp) {
      int fp = ptile0 + lg*2 + pp;
      int tree = fp>>8, lo = fp&255;
      int plocal = 255+lo;
      size_t chl = ((size_t)tree*1023 + 2*plocal + 1)*128;
      size_t wb = ((size_t)tree*511 + plocal)*512;
      #pragma unroll
      for (int s2=0; s2<2; ++s2) {
        int hcol = cs*32 + s2*16 + col0;
        #pragma unroll
        for (int g=0; g<4; ++g) wxv[pp][s2][g] = (float)wxb[wb + g*128 + hcol];
        cch[pp][s2][0] = cst[chl + hcol];
        cch[pp][s2][1] = cst[chl + 128 + hcol];
      }
    }

    f32x4 acc[8];
    #pragma unroll
    for (int gs=0; gs<8; ++gs) acc[gs] = (f32x4){0.f,0.f,0.f,0.f};
    #pragma unroll
    for (int ks=0; ks<4; ++ks) {
      #pragma unroll
      for (int gs=0; gs<8; ++gs) {
        bf16x8 b = ldsB(Blds, (gs>>1)*128 + cs*32 + (gs&1)*16 + col0, ks*64 + lg*16, 264);
        acc[gs] = __builtin_amdgcn_mfma_f32_16x16x32_bf16(a[ks], b, acc[gs], 0,0,0);
      }
    }

    #pragma unroll
    for (int pp=0; pp<2; ++pp) {
      int pib = mt*8 + lg*2 + pp;                       // parent index in block [0,32)
      #pragma unroll
      for (int s2=0; s2<2; ++s2) {
        int hcol = cs*32 + s2*16 + col0;
        float iv = acc[s2][2*pp]   + acc[s2][2*pp+1]   + wxv[pp][s2][0];
        float ov = acc[2+s2][2*pp] + acc[2+s2][2*pp+1] + wxv[pp][s2][1];
        float uv = acc[4+s2][2*pp] + acc[4+s2][2*pp+1] + wxv[pp][s2][2];
        float wf = wxv[pp][s2][3];
        float fl = sigf(acc[6+s2][2*pp]   + wf);
        float fr = sigf(acc[6+s2][2*pp+1] + wf);
        float cf = fl*cch[pp][s2][0] + fr*cch[pp][s2][1];
        float cn = sigf(iv)*tanh_fast(uv) + cf;
        float hn = sigf(ov)*tanh_fast(cn);
        st_c[pib][hcol] = cn;
        st_h[pib][hcol] = (bf16_t)hn;
      }
    }
  }
  __syncthreads();

  // ---- n=2 (shift=7): 16 order-2 parents, flat [16*blk, 16*blk+16), children in LDS
  {
    const int mt2 = rg;                                  // 2 mtiles, one per rowgroup
    int rr = lane&15;
    int crow = mt2*16 + rr;                              // order-1 child index in block
    bf16x8 a[4];
    #pragma unroll
    for (int ks=0; ks<4; ++ks)
      a[ks] = *(const bf16x8*)(&st_h[crow][ks*32 + lg*8]);

    float wxv[2][2][4], cch[2][2][2];
    int pnode[2];
    #pragma unroll
    for (int pp=0; pp<2; ++pp) {
      int pib = mt2*8 + lg*2 + pp;                       // order-2 parent in block [0,16)
      int f2 = blk*16 + pib;
      int tree = f2>>7, lo = f2&127;
      int plocal = 127+lo;
      pnode[pp] = tree*1023 + plocal;
      size_t wb = ((size_t)tree*511 + plocal)*512;
      #pragma unroll
      for (int s2=0; s2<2; ++s2) {
        int hcol = cs*32 + s2*16 + col0;
        #pragma unroll
        for (int g=0; g<4; ++g) wxv[pp][s2][g] = (float)wxb[wb + g*128 + hcol];
        cch[pp][s2][0] = st_c[2*pib][hcol];
        cch[pp][s2][1] = st_c[2*pib+1][hcol];
      }
    }

    f32x4 acc[8];
    #pragma unroll
    for (int gs=0; gs<8; ++gs) acc[gs] = (f32x4){0.f,0.f,0.f,0.f};
    #pragma unroll
    for (int ks=0; ks<4; ++ks) {
      #pragma unroll
      for (int gs=0; gs<8; ++gs) {
        bf16x8 b = ldsB(Blds, (gs>>1)*128 + cs*32 + (gs&1)*16 + col0, ks*64 + lg*16, 264);
        acc[gs] = __builtin_amdgcn_mfma_f32_16x16x32_bf16(a[ks], b, acc[gs], 0,0,0);
      }
    }

    #pragma unroll
    for (int pp=0; pp<2; ++pp) {
      #pragma unroll
      for (int s2=0; s2<2; ++s2) {
        int hcol = cs*32 + s2*16 + col0;
        float iv = acc[s2][2*pp]   + acc[s2][2*pp+1]   + wxv[pp][s2][0];
        float ov = acc[2+s2][2*pp] + acc[2+s2][2*pp+1] + wxv[pp][s2][1];
        float uv = acc[4+s2][2*pp] + acc[4+s2][2*pp+1] + wxv[pp][s2][2];
        float wf = wxv[pp][s2][3];
        float fl = sigf(acc[6+s2][2*pp]   + wf);
        float fr = sigf(acc[6+s2][2*pp+1] + wf);
        float cf = fl*cch[pp][s2][0] + fr*cch[pp][s2][1];
        float cn = sigf(iv)*tanh_fast(uv) + cf;
        float hn = sigf(ov)*tanh_fast(cn);
        cst[(size_t)pnode[pp]*128 + hcol] = cn;
        h[(size_t)pnode[pp]*128 + hcol] = (bf16_t)hn;
      }
    }
  }
}

// =================== kernel 3: tail levels n=3..9 + root head =================
__global__ __launch_bounds__(512) void k_tail(
    const float* __restrict__ U_iou, const float* __restrict__ U_f,
    const bf16_t* __restrict__ wxb, bf16_t* __restrict__ h, float* __restrict__ cst,
    const float* __restrict__ Wm, const float* __restrict__ bm,
    const float* __restrict__ Wv, const float* __restrict__ bv,
    const float* __restrict__ eps, float* __restrict__ out)
{
  __shared__ __align__(16) char Blds[135168];
  __shared__ float hs[128];
  const int tid = threadIdx.x, wave = tid>>6, lane = tid&63;
  const int rg = wave>>2, cs = wave&3, lg = lane>>4, col0 = lane&15;
  const int tree = blockIdx.x;
  const size_t hb = (size_t)tree*1023*128;

  stage_WU(U_iou, 384, U_f, 128, Blds, tid);
  __syncthreads();

  for (int n = 3; n <= 9; ++n) {
    const int P = 1 << (9-n);
    const int rows2 = 2*P;
    const int mtiles = (rows2 >= 16) ? (rows2 >> 4) : 1;
    const int cbase = 2*P - 1;

    for (int mt = rg; mt < mtiles; mt += 2) {
      const int rb = mt*16;
      int cr = rb + (lane&15);
      if (cr >= rows2) cr = 0;
      const bf16_t* hp = h + hb + (size_t)(cbase + cr)*128 + lg*8;
      bf16x8 a[4];
      #pragma unroll
      for (int ks=0; ks<4; ++ks) a[ks] = *(const bf16x8*)(hp + ks*32);

      float wxv[2][2][4], cch[2][2][2];
      int pj[2], plocal[2];
      #pragma unroll
      for (int pp=0; pp<2; ++pp) {
        pj[pp] = (rb>>1) + lg*2 + pp;
        plocal[pp] = P - 1 + pj[pp];
        if (pj[pp] < P) {
          size_t wb = ((size_t)tree*511 + plocal[pp])*512;
          size_t chl = hb + (size_t)(cbase + 2*pj[pp])*128;
          #pragma unroll
          for (int s2=0; s2<2; ++s2) {
            int hcol = cs*32 + s2*16 + col0;
            #pragma unroll
            for (int g=0; g<4; ++g) wxv[pp][s2][g] = (float)wxb[wb + g*128 + hcol];
            cch[pp][s2][0] = cst[chl + hcol];
            cch[pp][s2][1] = cst[chl + 128 + hcol];
          }
        }
      }

      f32x4 acc[8];
      #pragma unroll
      for (int gs=0; gs<8; ++gs) acc[gs] = (f32x4){0.f,0.f,0.f,0.f};
      #pragma unroll
      for (int ks=0; ks<4; ++ks) {
        #pragma unroll
        for (int gs=0; gs<8; ++gs) {
          bf16x8 b = ldsB(Blds, (gs>>1)*128 + cs*32 + (gs&1)*16 + col0, ks*64 + lg*16, 264);
          acc[gs] = __builtin_amdgcn_mfma_f32_16x16x32_bf16(a[ks], b, acc[gs], 0,0,0);
        }
      }

      #pragma unroll
      for (int pp=0; pp<2; ++pp) {
        if (pj[pp] < P) {
          size_t pno = hb + (size_t)plocal[pp]*128;
          #pragma unroll
          for (int s2=0; s2<2; ++s2) {
            int hcol = cs*32 + s2*16 + col0;
            float iv = acc[s2][2*pp]   + acc[s2][2*pp+1]   + wxv[pp][s2][0];
            float ov = acc[2+s2][2*pp] + acc[2+s2][2*pp+1] + wxv[pp][s2][1];
            float uv = acc[4+s2][2*pp] + acc[4+s2][2*pp+1] + wxv[pp][s2][2];
            float wf = wxv[pp][s2][3];
            float fl = sigf(acc[6+s2][2*pp]   + wf);
            float fr = sigf(acc[6+s2][2*pp+1] + wf);
            float cf = fl*cch[pp][s2][0] + fr*cch[pp][s2][1];
            float cn = sigf(iv)*tanh_fast(uv) + cf;
            float hn = sigf(ov)*tanh_fast(cn);
            cst[pno + hcol] = cn;
            h[pno + hcol] = (bf16_t)hn;
            if (n == 9) hs[hcol] = hn;     // only pj==0 reaches here at n=9
          }
        }
      }
    }
    __threadfence_block();
    __syncthreads();
  }

  // fused root head
  if (tid < 64) {
    const int j = tid;
    float am = 0.f, av = 0.f;
    #pragma unroll 4
    for (int i=0;i<128;++i) {
      float hv = hs[i];
      am += hv*Wm[i*64+j];
      av += hv*Wv[i*64+j];
    }
    float zm = am + bm[j];
    float zv = av + bv[j];
    int idx = tree*64 + j;
    out[idx]        = zm + eps[idx]*__expf(0.5f*zv);
    out[2048 + idx] = zm;
    out[4096 + idx] = zv;
  }
}

// =================== host launcher ============================================
extern "C" void kernel_launch(void* const* d_in, const int* in_sizes, int n_in,
                              void* d_out, int out_size, void* d_ws, size_t ws_size,
                              hipStream_t stream) {
  const int*   features = (const int*)  d_in[0];
  const int*   vocabs   = (const int*)  d_in[1];
  // d_in[2..5]: static topology (derived in-kernel)
  const float* eps      = (const float*)d_in[6];
  const float* emb_res  = (const float*)d_in[7];
  const float* emb_leaf = (const float*)d_in[8];
  const float* W_leaf   = (const float*)d_in[9];
  const float* b_leaf   = (const float*)d_in[10];
  const float* W_iou    = (const float*)d_in[11];
  const float* b_iou    = (const float*)d_in[12];
  const float* U_iou    = (const float*)d_in[13];
  const float* W_f      = (const float*)d_in[14];
  const float* b_f      = (const float*)d_in[15];
  const float* U_f      = (const float*)d_in[16];
  const float* Wm       = (const float*)d_in[17];
  const float* bm       = (const float*)d_in[18];
  const float* Wv       = (const float*)d_in[19];
  const float* bv       = (const float*)d_in[20];

  char* wsb = (char*)d_ws;
  bf16_t* h   = (bf16_t*)wsb;                                   // NNODES*128 bf16
  float*  cst = (float*)(wsb + 8388608);                        // NNODES*128 f32
  bf16_t* wxb = (bf16_t*)(wsb + 8388608 + 16777216);            // NINT*512 bf16
  float* out = (float*)d_out;

  k_prep_leaf<<<512, 512, 0, stream>>>(features, vocabs, emb_res, emb_leaf,
                                       W_iou, b_iou, W_f, b_f, W_leaf, b_leaf,
                                       wxb, h, cst);
  k_lvl12<<<256, 512, 0, stream>>>(U_iou, U_f, wxb, h, cst);
  k_tail<<<TREES, 512, 0, stream>>>(U_iou, U_f, wxb, h, cst,
                                    Wm, bm, Wv, bv, eps, out);
}

// Round 9
// 101.976 us; speedup vs baseline: 5.0638x; 1.4329x over previous
//
#include <hip/hip_runtime.h>

#define TREES 32
#define PER   1023
#define NIPT  511
#define NINT  (TREES*NIPT)      // 16352
#define VLEAF 5000

typedef __bf16 bf16_t;
typedef bf16_t bf16x4 __attribute__((ext_vector_type(4)));
typedef bf16_t bf16x8 __attribute__((ext_vector_type(8)));
typedef float  f32x4  __attribute__((ext_vector_type(4)));

__device__ __forceinline__ float sigf(float x) { return 1.0f/(1.0f+__expf(-x)); }
__device__ __forceinline__ float tanh_fast(float x) { return 2.0f/(1.0f+__expf(-2.0f*x)) - 1.0f; }

__device__ __forceinline__ bf16x8 to_bf16x8(const float* p) {
  float4 a = *(const float4*)p;
  float4 b = *(const float4*)(p+4);
  bf16x8 r;
  r[0]=(bf16_t)a.x; r[1]=(bf16_t)a.y; r[2]=(bf16_t)a.z; r[3]=(bf16_t)a.w;
  r[4]=(bf16_t)b.x; r[5]=(bf16_t)b.y; r[6]=(bf16_t)b.z; r[7]=(bf16_t)b.w;
  return r;
}
__device__ __forceinline__ bf16x8 zero_bf16x8() {
  bf16x8 r;
  #pragma unroll
  for (int i=0;i<8;++i) r[i]=(bf16_t)0.0f;
  return r;
}
__device__ __forceinline__ bf16x8 ldsB(const char* lds, int col, int kb, int rowb) {
  return *(const bf16x8*)(lds + col*rowb + kb);
}

// ---- load the per-wave U fragment set into registers (128 VGPR, needs launch_bounds(512,2))
__device__ __forceinline__ void load_breg(const float* __restrict__ U_iou,
                                          const float* __restrict__ U_f,
                                          int cs, int lg, int col0, bf16x8 breg[8][4]) {
  #pragma unroll
  for (int gs=0; gs<8; ++gs) {
    int col = (gs>>1)*128 + cs*32 + (gs&1)*16 + col0;
    const float* src; int ld;
    if (col < 384) { src = U_iou + col; ld = 384; }
    else           { src = U_f + (col-384); ld = 128; }
    #pragma unroll
    for (int ks=0; ks<4; ++ks) {
      #pragma unroll
      for (int i=0;i<8;++i) breg[gs][ks][i] = (bf16_t)src[(ks*32 + lg*8 + i)*ld];
    }
  }
}

__device__ __forceinline__ void mfma8(const bf16x8 a[4], const bf16x8 breg[8][4], f32x4 acc[8]) {
  #pragma unroll
  for (int ks=0; ks<4; ++ks) {
    #pragma unroll
    for (int gs=0; gs<8; ++gs)
      acc[gs] = __builtin_amdgcn_mfma_f32_16x16x32_bf16(a[ks], breg[gs][ks], acc[gs], 0,0,0);
  }
}

// LSTM combine: acc gs = {i:0,1 | o:2,3 | u:4,5 | f:6,7}, rows 2pp,2pp+1 = children L,R
__device__ __forceinline__ void lstm_epi(const f32x4 acc[8], const bf16x4 w4[2][2],
                                         const float2 cp[2][2],
                                         float hn[2][2], float cn[2][2]) {
  #pragma unroll
  for (int pp=0; pp<2; ++pp) {
    #pragma unroll
    for (int s2=0; s2<2; ++s2) {
      float iv = acc[s2][2*pp]   + acc[s2][2*pp+1]   + (float)w4[pp][s2][0];
      float ov = acc[2+s2][2*pp] + acc[2+s2][2*pp+1] + (float)w4[pp][s2][1];
      float uv = acc[4+s2][2*pp] + acc[4+s2][2*pp+1] + (float)w4[pp][s2][2];
      float wf = (float)w4[pp][s2][3];
      float fl = sigf(acc[6+s2][2*pp]   + wf);
      float fr = sigf(acc[6+s2][2*pp+1] + wf);
      float cf = fl*cp[pp][s2].x + fr*cp[pp][s2].y;
      float c  = sigf(iv)*tanh_fast(uv) + cf;
      cn[pp][s2] = c;
      hn[pp][s2] = sigf(ov)*tanh_fast(c);
    }
  }
}

// ---- LDS staging for prep/leaf weights (unchanged from R8)
__device__ __forceinline__ void stage_WU(const float* __restrict__ Wa, int lda,
                                         const float* __restrict__ Wb, int ldb,
                                         char* lds, int tid) {
  const float* src; int ld;
  if (tid < 384) { src = Wa + tid; ld = lda; }
  else           { src = Wb + (tid-384); ld = ldb; }
  #pragma unroll
  for (int k0 = 0; k0 < 128; k0 += 8) {
    bf16x8 r;
    #pragma unroll
    for (int i=0;i<8;++i) r[i] = (bf16_t)src[(k0+i)*ld];
    *(bf16x8*)(lds + tid*264 + k0*2) = r;
  }
}
__device__ __forceinline__ void stage_WL(const float* __restrict__ W_leaf, char* lds, int tid) {
  if (tid < 384) {
    int cm = tid < 128 ? tid : tid + 128;      // [gi,gg,go] from [gi,gf,gg,go]
    #pragma unroll
    for (int k0 = 0; k0 < 192; k0 += 8) {
      bf16x8 r;
      #pragma unroll
      for (int i=0;i<8;++i) {
        int k = k0+i;
        r[i] = (bf16_t)W_leaf[(k>>6)*32768 + (k&63)*512 + cm];
      }
      *(bf16x8*)(lds + tid*392 + k0*2) = r;
    }
  }
}

// =================== kernel 1: prep (blocks 0-255) | leaf (blocks 256-511) ====
__global__ __launch_bounds__(512) void k_prep_leaf(
    const int* __restrict__ features, const int* __restrict__ vocabs,
    const float* __restrict__ emb_res, const float* __restrict__ emb_leaf,
    const float* __restrict__ W_iou, const float* __restrict__ b_iou,
    const float* __restrict__ W_f, const float* __restrict__ b_f,
    const float* __restrict__ W_leaf, const float* __restrict__ b_leaf,
    bf16_t* __restrict__ wx4, bf16_t* __restrict__ hg, float* __restrict__ c2)
{
  __shared__ __align__(16) char Blds[150528];
  const int tid = threadIdx.x, wave = tid>>6, lane = tid&63;
  const int rg = wave>>2, cs = wave&3, lg = lane>>4, col0 = lane&15;

  if (blockIdx.x < 256) {
    // ===== prep: wx4[ci][hcol][g] = bf16(emb@[W_iou|W_f] + bias), g = {i,o,u,f}
    stage_WU(W_iou, 384, W_f, 128, Blds, tid);
    __syncthreads();
    #pragma unroll
    for (int mi=0; mi<2; ++mi) {
      int mt = rg + mi*2;
      int row0 = blockIdx.x*64 + mt*16;
      int rowA = row0 + (lane&15);
      if (rowA >= NINT) rowA = NINT-1;
      unsigned tree = (unsigned)rowA / 511u;
      int local = rowA - tree*511u;
      int feat = features[tree*1023 + local];
      const float* ep = emb_res + (size_t)feat*128 + lg*8;

      bf16x8 a[4];
      #pragma unroll
      for (int ks=0; ks<4; ++ks) a[ks] = to_bf16x8(ep + ks*32);

      f32x4 acc[8];
      #pragma unroll
      for (int j=0;j<8;++j) acc[j] = (f32x4){0.f,0.f,0.f,0.f};
      #pragma unroll
      for (int ks=0; ks<4; ++ks) {
        #pragma unroll
        for (int j=0; j<8; ++j) {
          bf16x8 b = ldsB(Blds, cs*128 + j*16 + col0, ks*64 + lg*16, 264);
          acc[j] = __builtin_amdgcn_mfma_f32_16x16x32_bf16(a[ks], b, acc[j], 0,0,0);
        }
      }
      #pragma unroll
      for (int j=0; j<8; ++j) {
        int c = cs*128 + j*16 + col0;
        float bias = (c < 384) ? b_iou[c] : b_f[c-384];
        #pragma unroll
        for (int r=0; r<4; ++r) {
          int ci = row0 + lg*4 + r;
          if (ci >= NINT) ci = NINT-1;
          wx4[(size_t)ci*512 + ((c&127)<<2) + (c>>7)] = (bf16_t)(acc[j][r] + bias);
        }
      }
    }
  } else {
    // ===== leaf: block-diag K=192 GEMM, writes h + paired c2
    stage_WL(W_leaf, Blds, tid);
    __syncthreads();
    #pragma unroll
    for (int mi=0; mi<2; ++mi) {
      int mt = rg + mi*2;
      const int base = (int)(blockIdx.x-256)*64 + mt*16;
      int rA = base + (lane&15);
      int treeA = rA>>9, loA = rA&511;
      int nodeA = treeA*1023 + 511 + loA;
      int kkA = vocabs[nodeA]-1;
      int featA = features[nodeA];
      const float* xp = emb_leaf + ((size_t)kkA*VLEAF + featA)*64;

      f32x4 acc[6];
      #pragma unroll
      for (int j=0;j<6;++j) acc[j] = (f32x4){0.f,0.f,0.f,0.f};
      #pragma unroll
      for (int ks=0; ks<6; ++ks) {
        int k0 = ks*32 + lg*8;
        bf16x8 a = ((k0>>6) == kkA) ? to_bf16x8(xp + (k0&63)) : zero_bf16x8();
        #pragma unroll
        for (int g=0; g<3; ++g) {
          #pragma unroll
          for (int s=0; s<2; ++s) {
            bf16x8 b = ldsB(Blds, g*128 + cs*32 + s*16 + col0, ks*64 + lg*16, 392);
            acc[g*2+s] = __builtin_amdgcn_mfma_f32_16x16x32_bf16(a, b, acc[g*2+s], 0,0,0);
          }
        }
      }
      #pragma unroll
      for (int r=0; r<4; ++r) {
        int L = base + lg*4 + r;
        int tree = L>>9, lo = L&511;
        int l = 511 + lo;
        int node = tree*1023 + l;
        int kk = vocabs[node]-1;
        const float* bl = b_leaf + kk*512;
        int pl = l - 1;
        size_t c2b = ((size_t)tree*511 + (pl>>1))*256;
        #pragma unroll
        for (int s=0; s<2; ++s) {
          int cc = cs*32 + s*16 + col0;
          float gi = acc[s][r]   + bl[cc];
          float gg = acc[2+s][r] + bl[256+cc];
          float go = acc[4+s][r] + bl[384+cc];
          float ck = sigf(gi)*tanh_fast(gg);
          float hk = sigf(go)*tanh_fast(ck);
          c2[c2b + cc*2 + (pl&1)] = ck;
          hg[(size_t)node*128+cc] = (bf16_t)hk;
        }
      }
    }
  }
}

// =================== kernel 2: levels 1..6, orders 1-5 entirely in LDS ========
// 256 blocks (8 per tree), each owns 32 order-1 parents; U in 128 VGPRs/wave
__global__ __launch_bounds__(512, 2) void k_levels(
    const float* __restrict__ U_iou, const float* __restrict__ U_f,
    const bf16_t* __restrict__ wx4, bf16_t* __restrict__ hg, float* __restrict__ c2)
{
  __shared__ __align__(16) bf16_t st_h[48][136];
  __shared__ float st_c[48][128];
  const int tid = threadIdx.x, wave = tid>>6, lane = tid&63;
  const int rg = wave>>2, cs = wave&3, lg = lane>>4, col0 = lane&15;
  const int blk = blockIdx.x, tree = blk>>3, b8 = blk&7;

  bf16x8 breg[8][4];
  load_breg(U_iou, U_f, cs, lg, col0, breg);

  // ---------- n=1: A = leaf h (global), c = c2 (global); out -> st rows 0..31
  #pragma unroll
  for (int mi=0; mi<2; ++mi) {
    int mt = rg + mi*2;
    int rr = lane&15;
    int fp = blk*32 + mt*8 + (rr>>1);          // flat order-1 parent (tree = fp>>8)
    int loA = fp & 255;
    int chA = tree*1023 + 2*(255+loA) + 1 + (rr&1);
    const bf16_t* hp = hg + (size_t)chA*128 + lg*8;
    bf16x8 a[4];
    #pragma unroll
    for (int ks=0; ks<4; ++ks) a[ks] = *(const bf16x8*)(hp + ks*32);

    bf16x4 w4[2][2]; float2 cp[2][2]; int pib[2];
    #pragma unroll
    for (int pp=0; pp<2; ++pp) {
      int pj = mt*8 + lg*2 + pp;
      pib[pp] = pj;
      size_t ci = (size_t)tree*511 + 255 + (b8*32 + pj);
      #pragma unroll
      for (int s2=0; s2<2; ++s2) {
        int hcol = cs*32 + s2*16 + col0;
        w4[pp][s2] = *(const bf16x4*)(wx4 + ci*512 + hcol*4);
        cp[pp][s2] = *(const float2*)(c2 + ci*256 + hcol*2);
      }
    }

    f32x4 acc[8];
    #pragma unroll
    for (int gs=0; gs<8; ++gs) acc[gs] = (f32x4){0.f,0.f,0.f,0.f};
    mfma8(a, breg, acc);
    float hn[2][2], cn[2][2];
    lstm_epi(acc, w4, cp, hn, cn);
    #pragma unroll
    for (int pp=0; pp<2; ++pp) {
      #pragma unroll
      for (int s2=0; s2<2; ++s2) {
        int hcol = cs*32 + s2*16 + col0;
        st_c[pib[pp]][hcol] = cn[pp][s2];
        st_h[pib[pp]][hcol] = (bf16_t)hn[pp][s2];
      }
    }
  }
  __syncthreads();

  // ---------- n=2: children = st rows 0..31; out -> st rows 32..47
  {
    int mt = rg;
    int rr = lane&15;
    int crow = mt*16 + rr;
    bf16x8 a[4];
    #pragma unroll
    for (int ks=0; ks<4; ++ks) a[ks] = *(const bf16x8*)(&st_h[crow][ks*32 + lg*8]);

    bf16x4 w4[2][2]; float2 cp[2][2]; int pib[2];
    #pragma unroll
    for (int pp=0; pp<2; ++pp) {
      int pj = mt*8 + lg*2 + pp;
      pib[pp] = 32 + pj;
      size_t ci = (size_t)tree*511 + 127 + (b8*16 + pj);
      #pragma unroll
      for (int s2=0; s2<2; ++s2) {
        int hcol = cs*32 + s2*16 + col0;
        w4[pp][s2] = *(const bf16x4*)(wx4 + ci*512 + hcol*4);
        cp[pp][s2] = make_float2(st_c[2*pj][hcol], st_c[2*pj+1][hcol]);
      }
    }

    f32x4 acc[8];
    #pragma unroll
    for (int gs=0; gs<8; ++gs) acc[gs] = (f32x4){0.f,0.f,0.f,0.f};
    mfma8(a, breg, acc);
    float hn[2][2], cn[2][2];
    lstm_epi(acc, w4, cp, hn, cn);
    #pragma unroll
    for (int pp=0; pp<2; ++pp) {
      #pragma unroll
      for (int s2=0; s2<2; ++s2) {
        int hcol = cs*32 + s2*16 + col0;
        st_c[pib[pp]][hcol] = cn[pp][s2];
        st_h[pib[pp]][hcol] = (bf16_t)hn[pp][s2];
      }
    }
  }
  __syncthreads();

  // ---------- n=3..6: rowgroup 0 only; st->st (n<6) or st->global (n=6)
  const int Pn_[4]   = {8, 4, 2, 1};
  const int cb_[4]   = {32, 0, 8, 12};     // child st row base
  const int ob_[4]   = {0, 8, 12, 0};      // out st row base (n<6)
  const int base_[4] = {63, 31, 15, 7};    // plocal base
  const int mul_[4]  = {8, 4, 2, 1};       // per-block parents
  #pragma unroll
  for (int li=0; li<4; ++li) {
    if (rg == 0) {
      const int Pn = Pn_[li], kc = 2*Pn_[li];
      int rr = lane&15;
      int r2 = (rr < kc) ? rr : 0;
      int crow = cb_[li] + r2;
      bf16x8 a[4];
      #pragma unroll
      for (int ks=0; ks<4; ++ks) a[ks] = *(const bf16x8*)(&st_h[crow][ks*32 + lg*8]);

      bf16x4 w4[2][2]; float2 cp[2][2]; int pj[2], plocal[2];
      #pragma unroll
      for (int pp=0; pp<2; ++pp) {
        pj[pp] = lg*2 + pp;
        plocal[pp] = base_[li] + b8*mul_[li] + pj[pp];
        size_t ci = (size_t)tree*511 + plocal[pp];
        int cr0 = cb_[li] + 2*pj[pp];
        #pragma unroll
        for (int s2=0; s2<2; ++s2) {
          int hcol = cs*32 + s2*16 + col0;
          w4[pp][s2] = *(const bf16x4*)(wx4 + ci*512 + hcol*4);
          cp[pp][s2] = make_float2(st_c[cr0][hcol], st_c[cr0+1][hcol]);
        }
      }

      f32x4 acc[8];
      #pragma unroll
      for (int gs=0; gs<8; ++gs) acc[gs] = (f32x4){0.f,0.f,0.f,0.f};
      mfma8(a, breg, acc);
      float hn[2][2], cn[2][2];
      lstm_epi(acc, w4, cp, hn, cn);
      #pragma unroll
      for (int pp=0; pp<2; ++pp) {
        if (pj[pp] < Pn) {
          #pragma unroll
          for (int s2=0; s2<2; ++s2) {
            int hcol = cs*32 + s2*16 + col0;
            if (li < 3) {
              st_c[ob_[li] + pj[pp]][hcol] = cn[pp][s2];
              st_h[ob_[li] + pj[pp]][hcol] = (bf16_t)hn[pp][s2];
            } else {
              // order-6 -> global (plocal = 7 + b8)
              int pl = plocal[pp] - 1;
              c2[((size_t)tree*511 + (pl>>1))*256 + hcol*2 + (pl&1)] = cn[pp][s2];
              hg[((size_t)tree*1023 + plocal[pp])*128 + hcol] = (bf16_t)hn[pp][s2];
            }
          }
        }
      }
    }
    __syncthreads();
  }
}

// =================== kernel 3: levels 7..9 + root head (1 block/tree) =========
__global__ __launch_bounds__(512, 2) void k_tail(
    const float* __restrict__ U_iou, const float* __restrict__ U_f,
    const bf16_t* __restrict__ wx4, bf16_t* __restrict__ hg, float* __restrict__ c2,
    const float* __restrict__ Wm, const float* __restrict__ bm,
    const float* __restrict__ Wv, const float* __restrict__ bv,
    const float* __restrict__ eps, float* __restrict__ out)
{
  __shared__ float hs[128];
  const int tid = threadIdx.x, wave = tid>>6, lane = tid&63;
  const int rg = wave>>2, cs = wave&3, lg = lane>>4, col0 = lane&15;
  const int tree = blockIdx.x;

  bf16x8 breg[8][4];
  load_breg(U_iou, U_f, cs, lg, col0, breg);

  const int Pn_[3]  = {4, 2, 1};
  const int chb_[3] = {7, 3, 1};     // child local base
  const int pb_[3]  = {3, 1, 0};     // parent local base
  #pragma unroll
  for (int li=0; li<3; ++li) {
    if (rg == 0) {
      const int Pn = Pn_[li], kc = 2*Pn_[li];
      int rr = lane&15;
      int r2 = (rr < kc) ? rr : 0;
      const bf16_t* hp = hg + ((size_t)tree*1023 + chb_[li] + r2)*128 + lg*8;
      bf16x8 a[4];
      #pragma unroll
      for (int ks=0; ks<4; ++ks) a[ks] = *(const bf16x8*)(hp + ks*32);

      bf16x4 w4[2][2]; float2 cp[2][2]; int pj[2], plocal[2];
      #pragma unroll
      for (int pp=0; pp<2; ++pp) {
        pj[pp] = lg*2 + pp;
        plocal[pp] = pb_[li] + pj[pp];
        size_t ci = (size_t)tree*511 + plocal[pp];
        #pragma unroll
        for (int s2=0; s2<2; ++s2) {
          int hcol = cs*32 + s2*16 + col0;
          w4[pp][s2] = *(const bf16x4*)(wx4 + ci*512 + hcol*4);
          cp[pp][s2] = *(const float2*)(c2 + ci*256 + hcol*2);
        }
      }

      f32x4 acc[8];
      #pragma unroll
      for (int gs=0; gs<8; ++gs) acc[gs] = (f32x4){0.f,0.f,0.f,0.f};
      mfma8(a, breg, acc);
      float hn[2][2], cn[2][2];
      lstm_epi(acc, w4, cp, hn, cn);
      #pragma unroll
      for (int pp=0; pp<2; ++pp) {
        if (pj[pp] < Pn) {
          #pragma unroll
          for (int s2=0; s2<2; ++s2) {
            int hcol = cs*32 + s2*16 + col0;
            if (li < 2) {
              int pl = plocal[pp] - 1;
              c2[((size_t)tree*511 + (pl>>1))*256 + hcol*2 + (pl&1)] = cn[pp][s2];
              hg[((size_t)tree*1023 + plocal[pp])*128 + hcol] = (bf16_t)hn[pp][s2];
            } else {
              hs[hcol] = hn[pp][s2];       // root h -> LDS only
            }
          }
        }
      }
    }
    __threadfence_block();
    __syncthreads();
  }

  // fused root head
  if (tid < 64) {
    const int j = tid;
    float am = 0.f, av = 0.f;
    #pragma unroll 4
    for (int i=0;i<128;++i) {
      float hv = hs[i];
      am += hv*Wm[i*64+j];
      av += hv*Wv[i*64+j];
    }
    float zm = am + bm[j];
    float zv = av + bv[j];
    int idx = tree*64 + j;
    out[idx]        = zm + eps[idx]*__expf(0.5f*zv);
    out[2048 + idx] = zm;
    out[4096 + idx] = zv;
  }
}

// =================== host launcher ============================================
extern "C" void kernel_launch(void* const* d_in, const int* in_sizes, int n_in,
                              void* d_out, int out_size, void* d_ws, size_t ws_size,
                              hipStream_t stream) {
  const int*   features = (const int*)  d_in[0];
  const int*   vocabs   = (const int*)  d_in[1];
  // d_in[2..5]: static topology (derived in-kernel)
  const float* eps      = (const float*)d_in[6];
  const float* emb_res  = (const float*)d_in[7];
  const float* emb_leaf = (const float*)d_in[8];
  const float* W_leaf   = (const float*)d_in[9];
  const float* b_leaf   = (const float*)d_in[10];
  const float* W_iou    = (const float*)d_in[11];
  const float* b_iou    = (const float*)d_in[12];
  const float* U_iou    = (const float*)d_in[13];
  const float* W_f      = (const float*)d_in[14];
  const float* b_f      = (const float*)d_in[15];
  const float* U_f      = (const float*)d_in[16];
  const float* Wm       = (const float*)d_in[17];
  const float* bm       = (const float*)d_in[18];
  const float* Wv       = (const float*)d_in[19];
  const float* bv       = (const float*)d_in[20];

  char* wsb = (char*)d_ws;
  bf16_t* hg  = (bf16_t*)wsb;                         // [NNODES][128] bf16
  float*  c2  = (float*)(wsb + 8388608);              // [TREES*511][128][2] f32 (child pairs)
  bf16_t* wx4 = (bf16_t*)(wsb + 8388608 + 16777216);  // [NINT][128][4] bf16 (gates i,o,u,f)
  float* out = (float*)d_out;

  k_prep_leaf<<<512, 512, 0, stream>>>(features, vocabs, emb_res, emb_leaf,
                                       W_iou, b_iou, W_f, b_f, W_leaf, b_leaf,
                                       wx4, hg, c2);
  k_levels<<<256, 512, 0, stream>>>(U_iou, U_f, wx4, hg, c2);
  k_tail<<<TREES, 512, 0, stream>>>(U_iou, U_f, wx4, hg, c2,
                                    Wm, bm, Wv, bv, eps, out);
}